// Round 3
// baseline (79.689 us; speedup 1.0000x reference)
//
#include <hip/hip_runtime.h>
#include <math.h>

#define B_ 32
#define C_ 64
#define L_ 16384
#define LT 64          // l-columns per tile
#define NT 8           // tiles per block (pipelined)
#define NBLK (B_ * (L_ / LT / NT))   // 1024 blocks

typedef __attribute__((ext_vector_type(8))) short short8;
typedef __attribute__((ext_vector_type(4))) float f32x4;

__device__ __forceinline__ unsigned short f2bf(float x) {
  unsigned int u = __builtin_bit_cast(unsigned int, x);
  u += 0x7fffu + ((u >> 16) & 1u);   // RNE
  return (unsigned short)(u >> 16);
}

__device__ __forceinline__ float lrelu(float x) {
  return x >= 0.f ? x : 0.1f * x;
}

__device__ __forceinline__ void load_lds_16(const void* g, void* l) {
  __builtin_amdgcn_global_load_lds(
      (const __attribute__((address_space(1))) void*)g,
      (__attribute__((address_space(3))) void*)l, 16, 0, 0);
}

// ---------------------------------------------------------------------------
// Prep: kern[b,c,3] = (lrelu(x1 W1^T)) W2^T ; att[b,c] = sigmoid(lrelu(x1 ca1^T) ca2^T)
// ---------------------------------------------------------------------------
__global__ void da_prep(const float* __restrict__ x1,
                        const float* __restrict__ W1,
                        const float* __restrict__ W2,
                        const float* __restrict__ ca_w1,
                        const float* __restrict__ ca_w2,
                        float* __restrict__ kern,
                        float* __restrict__ att) {
  int b = blockIdx.x;      // 32
  int t = threadIdx.x;     // 64
  __shared__ float x1s[64], h[64], a1[8];
  x1s[t] = x1[b * 64 + t];
  __syncthreads();
  {
    const float* w1r = W1 + t * 64;
    float s = 0.f;
    #pragma unroll
    for (int i = 0; i < 64; ++i) s = fmaf(x1s[i], w1r[i], s);
    h[t] = lrelu(s);
  }
  if (t < 8) {
    const float* cw = ca_w1 + t * 64;
    float a = 0.f;
    #pragma unroll
    for (int i = 0; i < 64; ++i) a = fmaf(x1s[i], cw[i], a);
    a1[t] = lrelu(a);
  }
  __syncthreads();
  #pragma unroll
  for (int kk = 0; kk < 3; ++kk) {
    const float* w2r = W2 + (t * 3 + kk) * 64;
    float s2 = 0.f;
    #pragma unroll
    for (int i = 0; i < 64; ++i) s2 = fmaf(h[i], w2r[i], s2);
    kern[(b * 64 + t) * 3 + kk] = s2;
  }
  {
    float a = 0.f;
    #pragma unroll
    for (int r = 0; r < 8; ++r) a = fmaf(a1[r], ca_w2[t * 8 + r], a);
    att[b * 64 + t] = 1.f / (1.f + expf(-a));
  }
}

// ---------------------------------------------------------------------------
// Main: NT-tile pipelined block.  Per tile: stage next tile (global_load_lds,
// source-preswizzled), counted-vmcnt wait + raw barrier, depthwise 3-tap +
// lrelu -> midT (bf16, swizzled), 1x1 conv via 16x16x32 bf16 MFMA, epilogue
// + conv_b + x0*att from LDS, stores.  vmcnt never drains to 0 in the loop.
//
// x0s rows: 64 f32 = 16 chunks of 16B; LDS chunk p of row c holds global
// chunk p^(c&7) (inverse-swizzled global source, linear LDS dest - G21).
// Read global word w of row c: x0s[c*64 + ((w&~3)^((c&7)<<2)) + (w&3)].
// midT: halfword idx = l*64 + (c ^ ((l&7)<<3)) -> conflict-free b128 reads.
// ---------------------------------------------------------------------------
__global__ __launch_bounds__(256, 3) void da_main(
    const float* __restrict__ x0,
    const float* __restrict__ conv_w,
    const float* __restrict__ conv_b,
    const float* __restrict__ kern,
    const float* __restrict__ att,
    float* __restrict__ out) {
  __shared__ float x0s[2][64 * LT];          // 2 x 16 KB
  __shared__ unsigned short midT[LT * 64];   // 8 KB
  __shared__ float cbs[64], atts[64];

  int bid = blockIdx.x;            // 0..1023
  int b = bid >> 5;                // 32 blocks per batch
  int base_l = (bid & 31) * (NT * LT);
  int tid = threadIdx.x;
  int lane = tid & 63;
  int wave = tid >> 6;

  int m_lane = lane & 15;          // MFMA row/col within 16
  int kbase = (lane >> 4) * 8;     // MFMA k base

  const float* xb = x0 + (size_t)(b * 64) * L_;

  // ---- Stage tile t0 into buffer d. Per wave: 4 instrs, 4 rows (1KB) each.
  auto STAGE = [&](int t0, int d) {
    int l0t = base_l + t0 * LT;
    int p = lane & 15;             // 16B chunk within row
    int r4 = lane >> 4;            // row within 4-row group
    #pragma unroll
    for (int i = 0; i < 4; ++i) {
      int c = wave * 16 + i * 4 + r4;
      const float* g = xb + (size_t)c * L_ + l0t + ((p ^ (c & 7)) << 2);
      load_lds_16(g, &x0s[d][(wave * 16 + i * 4) * LT]);
    }
  };

  // ---- Prologue staging first (latency overlaps the small loads below)
  STAGE(0, 0);
  float hp[2] = {0.f, 0.f}, hn[2] = {0.f, 0.f};   // halo regs (static idx)
  {
    int l0t = base_l;
    if (wave == 0 && l0t > 0) hp[0] = xb[(size_t)lane * L_ + l0t - 1];
    if (wave == 3 && l0t + LT < L_) hn[0] = xb[(size_t)lane * L_ + l0t + LT];
  }

  // ---- Small loads (consumed pre-loop; their waits don't stall the pipe)
  if (tid < 64) {
    cbs[tid] = conv_b[tid];
    atts[tid] = att[b * 64 + tid];
  }
  float k0, k1, k2;
  {
    const float* kr = kern + (b * 64 + lane) * 3;
    k0 = kr[0]; k1 = kr[1]; k2 = kr[2];
  }
  short8 af[2][4];                 // conv_w A-frags (bf16)
  #pragma unroll
  for (int kt = 0; kt < 2; ++kt) {
    #pragma unroll
    for (int mt = 0; mt < 4; ++mt) {
      const float* wr = conv_w + (mt * 16 + m_lane) * 64 + kt * 32 + kbase;
      float4 wa = *(const float4*)wr;
      float4 wb = *(const float4*)(wr + 4);
      short8 v;
      v[0] = (short)f2bf(wa.x); v[1] = (short)f2bf(wa.y);
      v[2] = (short)f2bf(wa.z); v[3] = (short)f2bf(wa.w);
      v[4] = (short)f2bf(wb.x); v[5] = (short)f2bf(wb.y);
      v[6] = (short)f2bf(wb.z); v[7] = (short)f2bf(wb.w);
      af[kt][mt] = v;
    }
  }

  // ---- Pipelined tile loop. Per-wave vmem/tile: 4 loads + <=1 halo + 16 stores.
  #pragma unroll
  for (int t = 0; t < NT; ++t) {
    const int d = t & 1;

    // a: issue next tile's loads + halos (into buf d^1, regs parity (t+1)&1)
    if (t + 1 < NT) {
      STAGE(t + 1, d ^ 1);
      int l0n = base_l + (t + 1) * LT;
      if (wave == 0) hp[(t + 1) & 1] = xb[(size_t)lane * L_ + l0n - 1];
      if (wave == 3)
        hn[(t + 1) & 1] = (l0n + LT < L_) ? xb[(size_t)lane * L_ + l0n + LT] : 0.f;
    }

    // b: counted wait for THIS tile's loads (never 0 mid-loop), then barrier
    if (t == 0)
      asm volatile("s_waitcnt vmcnt(4) lgkmcnt(0)" ::: "memory");
    else if (t == NT - 1)
      asm volatile("s_waitcnt vmcnt(16) lgkmcnt(0)" ::: "memory");
    else
      asm volatile("s_waitcnt vmcnt(20) lgkmcnt(0)" ::: "memory");
    __builtin_amdgcn_s_barrier();

    // c: Phase A — depthwise 3-tap + lrelu -> midT.  c=lane, 16 l per thread.
    {
      int c = lane;
      int w0 = wave * 16;
      const float* row = &x0s[d][c * LT];
      const int csw = (c & 7) << 2;

      float4 q[4];
      #pragma unroll
      for (int i = 0; i < 4; ++i)
        q[i] = *(const float4*)&row[((wave * 4 + i) ^ (c & 7)) << 2];

      float prev = (wave == 0)
          ? hp[t & 1]
          : row[(((w0 - 1) & ~3) ^ csw) + ((w0 - 1) & 3)];
      float nxt = (wave == 3)
          ? hn[t & 1]
          : row[(((w0 + 16) & ~3) ^ csw) + ((w0 + 16) & 3)];

      #pragma unroll
      for (int i = 0; i < 4; ++i) {
        float xa = q[i].x, xb2 = q[i].y, xc = q[i].z, xd = q[i].w;
        float xm1 = prev;
        if (i > 0) xm1 = q[i - 1].w;
        float xp1 = nxt;
        if (i < 3) xp1 = q[i + 1].x;
        float m0 = fmaf(k0, xm1, fmaf(k1, xa,  k2 * xb2));
        float m1 = fmaf(k0, xa,  fmaf(k1, xb2, k2 * xc));
        float m2 = fmaf(k0, xb2, fmaf(k1, xc,  k2 * xd));
        float m3 = fmaf(k0, xc,  fmaf(k1, xd,  k2 * xp1));
        int l = w0 + 4 * i;
        midT[(l + 0) * 64 + (c ^ (((l + 0) & 7) << 3))] = f2bf(lrelu(m0));
        midT[(l + 1) * 64 + (c ^ (((l + 1) & 7) << 3))] = f2bf(lrelu(m1));
        midT[(l + 2) * 64 + (c ^ (((l + 2) & 7) << 3))] = f2bf(lrelu(m2));
        midT[(l + 3) * 64 + (c ^ (((l + 3) & 7) << 3))] = f2bf(lrelu(m3));
      }
    }

    // d: midT visible to all waves
    asm volatile("s_waitcnt lgkmcnt(0)" ::: "memory");
    __builtin_amdgcn_s_barrier();

    // e: Phase B — out[o][l] += W[o][c]*mid[c][l] via 16x16x32 bf16 MFMA
    f32x4 acc[4];
    #pragma unroll
    for (int mt = 0; mt < 4; ++mt) acc[mt] = (f32x4){0.f, 0.f, 0.f, 0.f};
    int lw = wave * 16;
    #pragma unroll
    for (int kt = 0; kt < 2; ++kt) {
      int l = lw + m_lane;
      int cb = kt * 32 + kbase;
      const short8 bf = *(const short8*)&midT[l * 64 + (cb ^ ((l & 7) << 3))];
      #pragma unroll
      for (int mt = 0; mt < 4; ++mt)
        acc[mt] = __builtin_amdgcn_mfma_f32_16x16x32_bf16(af[kt][mt], bf,
                                                          acc[mt], 0, 0, 0);
    }

    // f: epilogue — + conv_b + x0*att (from LDS), coalesced stores
    {
      int l0t = base_l + t * LT;
      int r0 = (lane >> 4) * 4;
      int w = lw + m_lane;
      #pragma unroll
      for (int mt = 0; mt < 4; ++mt) {
        #pragma unroll
        for (int r = 0; r < 4; ++r) {
          int o = mt * 16 + r0 + r;
          float xv = x0s[d][o * LT + (((w & ~3) ^ ((o & 7) << 2)) + (w & 3))];
          out[(size_t)(b * 64 + o) * L_ + l0t + w] =
              acc[mt][r] + cbs[o] + xv * atts[o];
        }
      }
    }

    // g: all waves done reading buf[d] + midT before next iter overwrites
    if (t + 1 < NT) {
      asm volatile("s_waitcnt lgkmcnt(0)" ::: "memory");
      __builtin_amdgcn_s_barrier();
    }
  }
}

extern "C" void kernel_launch(void* const* d_in, const int* in_sizes, int n_in,
                              void* d_out, int out_size, void* d_ws, size_t ws_size,
                              hipStream_t stream) {
  const float* x0     = (const float*)d_in[0];
  const float* x1     = (const float*)d_in[1];
  const float* W1     = (const float*)d_in[2];
  const float* W2     = (const float*)d_in[3];
  const float* conv_w = (const float*)d_in[4];
  const float* conv_b = (const float*)d_in[5];
  const float* ca_w1  = (const float*)d_in[6];
  const float* ca_w2  = (const float*)d_in[7];
  float* out = (float*)d_out;

  float* kern = (float*)d_ws;                 // B*C*3 = 6144 floats
  float* att  = kern + B_ * C_ * 3;           // B*C   = 2048 floats

  da_prep<<<dim3(B_), dim3(64), 0, stream>>>(x1, W1, W2, ca_w1, ca_w2, kern, att);
  da_main<<<dim3(NBLK), dim3(256), 0, stream>>>(x0, conv_w, conv_b,
                                                kern, att, out);
}

// Round 4
// 73.876 us; speedup vs baseline: 1.0787x; 1.0787x over previous
//
#include <hip/hip_runtime.h>
#include <math.h>

#define B_ 32
#define C_ 64
#define L_ 16384
#define LT 64                          // l-columns per block tile
#define NBLK (B_ * (L_ / LT))          // 8192 blocks

typedef __attribute__((ext_vector_type(8))) short short8;
typedef __attribute__((ext_vector_type(4))) float f32x4;

__device__ __forceinline__ unsigned short f2bf(float x) {
  unsigned int u = __builtin_bit_cast(unsigned int, x);
  u += 0x7fffu + ((u >> 16) & 1u);   // RNE
  return (unsigned short)(u >> 16);
}

__device__ __forceinline__ float lrelu(float x) {
  return x >= 0.f ? x : 0.1f * x;
}

__device__ __forceinline__ void load_lds_16(const void* g, void* l) {
  __builtin_amdgcn_global_load_lds(
      (const __attribute__((address_space(1))) void*)g,
      (__attribute__((address_space(3))) void*)l, 16, 0, 0);
}

// ---------------------------------------------------------------------------
// Prep (tiny): kern4[b,c,4] = depthwise kernels (stride-4 padded);
// att[b,c] = sigmoid(lrelu(x1 ca1^T) ca2^T);
// wfrag = conv_w as bf16 MFMA A-fragments in per-lane load order:
//   wfrag[((kt*4+mt)*64 + lane)*8 + j] = bf16(conv_w[mt*16+(lane&15)][kt*32+(lane>>4)*8+j])
// ---------------------------------------------------------------------------
__global__ void da_prep(const float* __restrict__ x1,
                        const float* __restrict__ W1,
                        const float* __restrict__ W2,
                        const float* __restrict__ ca_w1,
                        const float* __restrict__ ca_w2,
                        const float* __restrict__ conv_w,
                        float* __restrict__ kern4,
                        float* __restrict__ att,
                        unsigned short* __restrict__ wfrag) {
  int b = blockIdx.x;      // 32
  int t = threadIdx.x;     // 64
  __shared__ float x1s[64], h[64], a1[8];
  x1s[t] = x1[b * 64 + t];
  __syncthreads();
  {
    const float* w1r = W1 + t * 64;
    float s = 0.f;
    #pragma unroll
    for (int i = 0; i < 64; ++i) s = fmaf(x1s[i], w1r[i], s);
    h[t] = lrelu(s);
  }
  if (t < 8) {
    const float* cw = ca_w1 + t * 64;
    float a = 0.f;
    #pragma unroll
    for (int i = 0; i < 64; ++i) a = fmaf(x1s[i], cw[i], a);
    a1[t] = lrelu(a);
  }
  __syncthreads();
  #pragma unroll
  for (int kk = 0; kk < 3; ++kk) {
    const float* w2r = W2 + (t * 3 + kk) * 64;
    float s2 = 0.f;
    #pragma unroll
    for (int i = 0; i < 64; ++i) s2 = fmaf(h[i], w2r[i], s2);
    kern4[(b * 64 + t) * 4 + kk] = s2;
  }
  kern4[(b * 64 + t) * 4 + 3] = 0.f;
  {
    float a = 0.f;
    #pragma unroll
    for (int r = 0; r < 8; ++r) a = fmaf(a1[r], ca_w2[t * 8 + r], a);
    att[b * 64 + t] = 1.f / (1.f + expf(-a));
  }
  if (b == 0) {
    #pragma unroll
    for (int kt = 0; kt < 2; ++kt)
      #pragma unroll
      for (int mt = 0; mt < 4; ++mt)
        #pragma unroll
        for (int j = 0; j < 8; ++j) {
          float e = conv_w[(mt * 16 + (t & 15)) * 64 + kt * 32 + (t >> 4) * 8 + j];
          wfrag[(((kt * 4 + mt) * 64) + t) * 8 + j] = f2bf(e);
        }
  }
}

// ---------------------------------------------------------------------------
// Main: one (b, 64-l) tile per block, 8192 blocks, 6 blocks/CU (24.75 KB LDS).
// Serial block, latency hidden by TLP across resident blocks:
//   stage x0 tile (global_load_lds, source-preswizzled) + all small loads
//   -> sync -> depthwise+lrelu -> midT(bf16, swizzled) -> sync
//   -> 1x1 conv via 16x16x32 bf16 MFMA -> +bias +x0*att -> stores.
//
// x0s rows: 64 f32 = 16 chunks of 16B; LDS chunk p of row c holds global
// chunk p^(c&7).  Read word w of row c: x0s[c*64 + ((w&~3)^((c&7)<<2)) + (w&3)].
// midT: halfword idx = l*64 + (c ^ ((l&7)<<3)).  Both verified conflict-free.
// ---------------------------------------------------------------------------
__global__ __launch_bounds__(256, 6) void da_main(
    const float* __restrict__ x0,
    const float* __restrict__ conv_b,
    const float* __restrict__ kern4,
    const float* __restrict__ att,
    const unsigned short* __restrict__ wfrag,
    float* __restrict__ out) {
  __shared__ float x0s[64 * LT];             // 16 KB
  __shared__ unsigned short midT[LT * 64];   // 8 KB
  __shared__ float cbs[64], atts[64];

  int bid = blockIdx.x;            // 0..8191
  int b = bid >> 8;                // 256 tiles per batch
  int l0 = (bid & 255) * LT;
  int tid = threadIdx.x;
  int lane = tid & 63;
  int wave = tid >> 6;

  int m_lane = lane & 15;          // MFMA row/col within 16
  int kbase = (lane >> 4) * 8;     // MFMA k base

  const float* xb = x0 + (size_t)(b * 64) * L_;

  // ---- Stage x0 tile: 4 async 1KB global_load_lds per wave
  {
    int p = lane & 15;             // 16B chunk within row
    int r4 = lane >> 4;            // row within 4-row group
    #pragma unroll
    for (int i = 0; i < 4; ++i) {
      int c = wave * 16 + i * 4 + r4;
      const float* g = xb + (size_t)c * L_ + l0 + ((p ^ (c & 7)) << 2);
      load_lds_16(g, &x0s[(wave * 16 + i * 4) * LT]);
    }
  }

  // ---- Small loads overlapping the staging latency
  short8 af[2][4];                 // conv_w A-frags (pre-converted bf16)
  #pragma unroll
  for (int kt = 0; kt < 2; ++kt)
    #pragma unroll
    for (int mt = 0; mt < 4; ++mt)
      af[kt][mt] = *(const short8*)&wfrag[(((kt * 4 + mt) * 64) + lane) * 8];

  float4 kv = *(const float4*)&kern4[(b * 64 + lane) * 4];
  float k0 = kv.x, k1 = kv.y, k2 = kv.z;

  float hp = 0.f, hn = 0.f;        // halo elements (wave-uniform branches)
  if (wave == 0 && l0 > 0) hp = xb[(size_t)lane * L_ + l0 - 1];
  if (wave == 3 && l0 + LT < L_) hn = xb[(size_t)lane * L_ + l0 + LT];

  if (tid < 64) {
    cbs[tid] = conv_b[tid];
    atts[tid] = att[b * 64 + tid];
  }

  __syncthreads();   // drains vmcnt(0) + lgkmcnt(0): tile + halos ready

  // ---- Phase A: depthwise 3-tap + lrelu -> midT.  c=lane, 16 l per thread.
  {
    int c = lane;
    int w0 = wave * 16;
    const float* row = &x0s[c * LT];
    const int csw = (c & 7) << 2;

    float4 q[4];
    #pragma unroll
    for (int i = 0; i < 4; ++i)
      q[i] = *(const float4*)&row[((wave * 4 + i) ^ (c & 7)) << 2];

    float prev, nxt;
    if (wave == 0) {
      prev = hp;
    } else {
      int w = w0 - 1;
      prev = row[((w & ~3) ^ csw) + (w & 3)];
    }
    if (wave == 3) {
      nxt = hn;
    } else {
      int w = w0 + 16;
      nxt = row[((w & ~3) ^ csw) + (w & 3)];
    }

    #pragma unroll
    for (int i = 0; i < 4; ++i) {
      float xa = q[i].x, xb2 = q[i].y, xc = q[i].z, xd = q[i].w;
      float xm1 = prev;
      if (i > 0) xm1 = q[i - 1].w;
      float xp1 = nxt;
      if (i < 3) xp1 = q[i + 1].x;
      float m0 = fmaf(k0, xm1, fmaf(k1, xa,  k2 * xb2));
      float m1 = fmaf(k0, xa,  fmaf(k1, xb2, k2 * xc));
      float m2 = fmaf(k0, xb2, fmaf(k1, xc,  k2 * xd));
      float m3 = fmaf(k0, xc,  fmaf(k1, xd,  k2 * xp1));
      int l = w0 + 4 * i;
      midT[(l + 0) * 64 + (c ^ (((l + 0) & 7) << 3))] = f2bf(lrelu(m0));
      midT[(l + 1) * 64 + (c ^ (((l + 1) & 7) << 3))] = f2bf(lrelu(m1));
      midT[(l + 2) * 64 + (c ^ (((l + 2) & 7) << 3))] = f2bf(lrelu(m2));
      midT[(l + 3) * 64 + (c ^ (((l + 3) & 7) << 3))] = f2bf(lrelu(m3));
    }
  }
  __syncthreads();

  // ---- Phase B: out[o][l] = sum_c W[o][c]*mid[c][l] via 16x16x32 bf16 MFMA
  f32x4 acc[4];
  #pragma unroll
  for (int mt = 0; mt < 4; ++mt) acc[mt] = (f32x4){0.f, 0.f, 0.f, 0.f};
  int lw = wave * 16;
  #pragma unroll
  for (int kt = 0; kt < 2; ++kt) {
    int l = lw + m_lane;
    int cb = kt * 32 + kbase;
    const short8 bf = *(const short8*)&midT[l * 64 + (cb ^ ((l & 7) << 3))];
    #pragma unroll
    for (int mt = 0; mt < 4; ++mt)
      acc[mt] = __builtin_amdgcn_mfma_f32_16x16x32_bf16(af[kt][mt], bf,
                                                        acc[mt], 0, 0, 0);
  }

  // ---- Epilogue: + conv_b + x0*att (x0 from LDS, f32), coalesced stores
  {
    int r0 = (lane >> 4) * 4;
    int w = lw + m_lane;
    #pragma unroll
    for (int mt = 0; mt < 4; ++mt) {
      #pragma unroll
      for (int r = 0; r < 4; ++r) {
        int o = mt * 16 + r0 + r;
        float xv = x0s[o * LT + (((w & ~3) ^ ((o & 7) << 2)) + (w & 3))];
        out[(size_t)(b * 64 + o) * L_ + l0 + w] =
            acc[mt][r] + cbs[o] + xv * atts[o];
      }
    }
  }
}

extern "C" void kernel_launch(void* const* d_in, const int* in_sizes, int n_in,
                              void* d_out, int out_size, void* d_ws, size_t ws_size,
                              hipStream_t stream) {
  const float* x0     = (const float*)d_in[0];
  const float* x1     = (const float*)d_in[1];
  const float* W1     = (const float*)d_in[2];
  const float* W2     = (const float*)d_in[3];
  const float* conv_w = (const float*)d_in[4];
  const float* conv_b = (const float*)d_in[5];
  const float* ca_w1  = (const float*)d_in[6];
  const float* ca_w2  = (const float*)d_in[7];
  float* out = (float*)d_out;

  float* kern4 = (float*)d_ws;                      // 32*64*4 = 8192 f
  float* att   = kern4 + B_ * C_ * 4;               // 2048 f
  unsigned short* wfrag = (unsigned short*)(att + B_ * C_);  // 4096 bf16

  da_prep<<<dim3(B_), dim3(64), 0, stream>>>(x1, W1, W2, ca_w1, ca_w2, conv_w,
                                             kern4, att, wfrag);
  da_main<<<dim3(NBLK), dim3(256), 0, stream>>>(x0, conv_b, kern4, att, wfrag,
                                                out);
}